// Round 1
// baseline (851.566 us; speedup 1.0000x reference)
//
#include <hip/hip_runtime.h>
#include <math.h>

#define CC   256
#define HW   4096
#define OC3  384
#define HID  128
#define HEADS 4
#define DH   32
#define NM   4
#define SCALE 0.17677669529663688f  // 32^-0.5

// ---------------- prep: wq2t[c][o] = w_qkv[o][c]*g1[c]*16 ; woutt[e][oc] = w_out[oc][e]
__global__ void k_prep(const float* __restrict__ wqkv, const float* __restrict__ g1,
                       const float* __restrict__ wout,
                       float* __restrict__ wq2t, float* __restrict__ woutt) {
    int c = blockIdx.x;      // 0..255
    int t = threadIdx.x;     // 0..255
    float gs = g1[c] * 16.0f;
    for (int o = t; o < OC3; o += 256)
        wq2t[(size_t)c * OC3 + o] = wqkv[(size_t)o * CC + c] * gs;
    if (c < HID)
        woutt[(size_t)c * CC + t] = wout[(size_t)t * HID + c];
}

// ---------------- per-pixel inverse L2 norm over channels
__global__ void k_rnorm(const float* __restrict__ x, float* __restrict__ rn) {
    int pix = blockIdx.x * 256 + threadIdx.x;   // 0..131071
    int b = pix >> 12, hw = pix & 4095;
    const float* xp = x + (size_t)b * CC * HW + hw;
    float s = 0.f;
    #pragma unroll 8
    for (int c = 0; c < CC; ++c) { float v = xp[(size_t)c * HW]; s += v * v; }
    rn[pix] = 1.0f / fmaxf(sqrtf(s), 1e-12f);
}

// ---------------- qkv GEMM: BM=128 BN=64 BK=16, fused rms-norm scaling
__global__ __launch_bounds__(256) void k_qkv(const float* __restrict__ x,
        const float* __restrict__ wq2t, const float* __restrict__ rn,
        float* __restrict__ qkv) {
    __shared__ float As[16][128];
    __shared__ float Bs[16][64];
    __shared__ float rs[64];
    int tid = threadIdx.x;
    int pixblk = blockIdx.x;            // 0..2047  (64 pixels each)
    int mBase = blockIdx.y * 128;       // 0,128,256
    int b = pixblk >> 6;
    int hwb = (pixblk & 63) * 64;
    if (tid < 64) rs[tid] = rn[pixblk * 64 + tid];
    int tn = tid & 15, tm = tid >> 4;   // tn: 4 pix, tm: 8 oc
    float acc[8][4];
    #pragma unroll
    for (int i = 0; i < 8; ++i)
        #pragma unroll
        for (int j = 0; j < 4; ++j) acc[i][j] = 0.f;
    const float* xb = x + (size_t)b * CC * HW + hwb;
    for (int k0 = 0; k0 < CC; k0 += 16) {
        __syncthreads();
        #pragma unroll
        for (int q = 0; q < 8; ++q) {        // A: 128x16
            int idx = tid + q * 256;
            int kk = idx >> 7, o = idx & 127;
            As[kk][o] = wq2t[(size_t)(k0 + kk) * OC3 + mBase + o];
        }
        #pragma unroll
        for (int q = 0; q < 4; ++q) {        // B: 16x64 (scaled)
            int idx = tid + q * 256;
            int kk = idx >> 6, p = idx & 63;
            Bs[kk][p] = xb[(size_t)(k0 + kk) * HW + p] * rs[p];
        }
        __syncthreads();
        #pragma unroll 4
        for (int kk = 0; kk < 16; ++kk) {
            float4 a0 = *(const float4*)&As[kk][tm * 8];
            float4 a1 = *(const float4*)&As[kk][tm * 8 + 4];
            float4 b4 = *(const float4*)&Bs[kk][tn * 4];
            float av[8] = {a0.x, a0.y, a0.z, a0.w, a1.x, a1.y, a1.z, a1.w};
            float bv[4] = {b4.x, b4.y, b4.z, b4.w};
            #pragma unroll
            for (int i = 0; i < 8; ++i)
                #pragma unroll
                for (int j = 0; j < 4; ++j) acc[i][j] += av[i] * bv[j];
        }
    }
    #pragma unroll
    for (int i = 0; i < 8; ++i) {
        int o = mBase + tm * 8 + i;
        float* op = qkv + ((size_t)b * OC3 + o) * HW + hwb + tn * 4;
        *(float4*)op = make_float4(acc[i][0], acc[i][1], acc[i][2], acc[i][3]);
    }
}

// ---------------- k-softmax stats: one wave per (b,h,d) row, 4100 entries
__global__ void k_ksoft(const float* __restrict__ qkv, const float* __restrict__ memkv,
                        float* __restrict__ kmaxb, float* __restrict__ rsumb) {
    int row = blockIdx.x * 4 + (threadIdx.x >> 6);  // 0..4095 = b*128 + h*32 + d
    int lane = threadIdx.x & 63;
    int b = row >> 7, hd = row & 127;
    const float* kp = qkv + ((size_t)b * OC3 + HID + hd) * HW;
    float m = -1e30f;
    for (int i = lane; i < HW; i += 64) m = fmaxf(m, kp[i]);
    #pragma unroll
    for (int s = 1; s < 64; s <<= 1) m = fmaxf(m, __shfl_xor(m, s));
    const float* mk = memkv + hd * NM;
    #pragma unroll
    for (int j = 0; j < NM; ++j) m = fmaxf(m, mk[j]);
    float s = 0.f;
    for (int i = lane; i < HW; i += 64) s += __expf(kp[i] - m);
    #pragma unroll
    for (int t = 1; t < 64; t <<= 1) s += __shfl_xor(s, t);
    #pragma unroll
    for (int j = 0; j < NM; ++j) s += __expf(mk[j] - m);
    if (lane == 0) { kmaxb[row] = m; rsumb[row] = 1.0f / s; }
}

// ---------------- context: ctx[b,h,d,e] = sum_n softk[d,n]*v[e,n]; n split in 2 halves
__global__ __launch_bounds__(256) void k_ctx(const float* __restrict__ qkv,
        const float* __restrict__ memkv, const float* __restrict__ kmaxb,
        const float* __restrict__ rsumb, float* __restrict__ ctxp) {
    __shared__ float kl[DH][65];
    __shared__ float vl[DH][65];
    __shared__ float red[256 * 33];
    int tid = threadIdx.x;
    int bh = blockIdx.x >> 1;       // 0..127
    int half = blockIdx.x & 1;
    int b = bh >> 2, h = bh & 3;
    const float* kp = qkv + ((size_t)b * OC3 + HID + h * DH) * HW + half * 2048;
    const float* vp = qkv + ((size_t)b * OC3 + 2 * HID + h * DH) * HW + half * 2048;
    int slot = tid & 31, nng = tid >> 5;    // 32 slots x 8 n-groups
    int d0 = (slot >> 2) * 4, e0 = (slot & 3) * 8;
    int rowbase = bh * DH;
    float acc[4][8];
    #pragma unroll
    for (int i = 0; i < 4; ++i)
        #pragma unroll
        for (int j = 0; j < 8; ++j) acc[i][j] = 0.f;
    for (int n0 = 0; n0 < 2048; n0 += 64) {
        __syncthreads();
        #pragma unroll
        for (int q = 0; q < 8; ++q) {
            int idx = tid + q * 256;
            int r = idx >> 6, nn = idx & 63;
            float kraw = kp[(size_t)r * HW + n0 + nn];
            kl[r][nn] = __expf(kraw - kmaxb[rowbase + r]) * rsumb[rowbase + r];
            vl[r][nn] = vp[(size_t)r * HW + n0 + nn];
        }
        __syncthreads();
        #pragma unroll 2
        for (int t = 0; t < 8; ++t) {
            int nn = nng * 8 + t;
            float kv[4], vv[8];
            #pragma unroll
            for (int i = 0; i < 4; ++i) kv[i] = kl[d0 + i][nn];
            #pragma unroll
            for (int j = 0; j < 8; ++j) vv[j] = vl[e0 + j][nn];
            #pragma unroll
            for (int i = 0; i < 4; ++i)
                #pragma unroll
                for (int j = 0; j < 8; ++j) acc[i][j] += kv[i] * vv[j];
        }
    }
    __syncthreads();
    #pragma unroll
    for (int i = 0; i < 4; ++i)
        #pragma unroll
        for (int j = 0; j < 8; ++j) red[tid * 33 + i * 8 + j] = acc[i][j];
    __syncthreads();
    #pragma unroll
    for (int q = 0; q < 4; ++q) {
        int o = tid * 4 + q;            // d*32 + e
        int d = o >> 5, e = o & 31;
        int sl = (d >> 2) * 4 + (e >> 3);
        int k = (d & 3) * 8 + (e & 7);
        float s = 0.f;
        #pragma unroll
        for (int g = 0; g < 8; ++g) s += red[(g * 32 + sl) * 33 + k];
        if (half == 0) {   // memory kv contribution added once
            float km = kmaxb[rowbase + d], rsm = rsumb[rowbase + d];
            #pragma unroll
            for (int m = 0; m < NM; ++m) {
                float kw = __expf(memkv[(h * DH + d) * NM + m] - km) * rsm;
                s += kw * memkv[512 + (h * DH + e) * NM + m];
            }
        }
        ctxp[(size_t)half * 131072 + (size_t)bh * 1024 + o] = s;
    }
}

// ---------------- q softmax + apply context: outb[b,hid,n]
__global__ __launch_bounds__(256) void k_attn(const float* __restrict__ qkv,
        const float* __restrict__ ctxp, float* __restrict__ outb) {
    __shared__ float qs[128][68];
    __shared__ float cs[4096];
    int tid = threadIdx.x;
    int pixblk = blockIdx.x;
    int b = pixblk >> 6;
    int hwb = (pixblk & 63) * 64;
    const float* qp = qkv + (size_t)b * OC3 * HW + hwb;
    #pragma unroll
    for (int q = 0; q < 32; ++q) {
        int idx = tid + q * 256;
        int r = idx >> 6, p = idx & 63;
        qs[r][p] = qp[(size_t)r * HW + p];
    }
    #pragma unroll
    for (int q = 0; q < 16; ++q) {
        int i = tid + q * 256;
        cs[i] = ctxp[(size_t)b * 4096 + i] + ctxp[131072 + (size_t)b * 4096 + i];
    }
    __syncthreads();
    {   // softmax over d for (h = tid>>6, p = tid&63) — thread owns its column
        int h = tid >> 6, p = tid & 63;
        float m = -1e30f;
        #pragma unroll
        for (int d = 0; d < DH; ++d) m = fmaxf(m, qs[h * DH + d][p]);
        float s = 0.f;
        #pragma unroll
        for (int d = 0; d < DH; ++d) s += __expf(qs[h * DH + d][p] - m);
        float r_ = SCALE / s;
        #pragma unroll
        for (int d = 0; d < DH; ++d) qs[h * DH + d][p] = __expf(qs[h * DH + d][p] - m) * r_;
    }
    __syncthreads();
    int p4 = tid & 15, eg = tid >> 4;
    int p = p4 * 4, r0 = eg * 8;
    int h = r0 >> 5, el = r0 & 31;
    float acc[8][4];
    #pragma unroll
    for (int i = 0; i < 8; ++i)
        #pragma unroll
        for (int j = 0; j < 4; ++j) acc[i][j] = 0.f;
    #pragma unroll 4
    for (int d = 0; d < DH; ++d) {
        float4 q4 = *(const float4*)&qs[h * DH + d][p];
        float qv[4] = {q4.x, q4.y, q4.z, q4.w};
        #pragma unroll
        for (int i = 0; i < 8; ++i) {
            float cv = cs[(h * DH + d) * DH + el + i];
            #pragma unroll
            for (int j = 0; j < 4; ++j) acc[i][j] += cv * qv[j];
        }
    }
    #pragma unroll
    for (int i = 0; i < 8; ++i) {
        float* op = outb + ((size_t)b * HID + r0 + i) * HW + hwb + p;
        *(float4*)op = make_float4(acc[i][0], acc[i][1], acc[i][2], acc[i][3]);
    }
}

// ---------------- final GEMM (256x128) + bias + fused rms-norm*g2*16
__global__ __launch_bounds__(256) void k_final(const float* __restrict__ outb,
        const float* __restrict__ woutt, const float* __restrict__ bout,
        const float* __restrict__ g2, float* __restrict__ y) {
    __shared__ float wl[32][256];
    __shared__ float ol[32][64];
    __shared__ float red[16][64];
    __shared__ float invs[64];
    int tid = threadIdx.x;
    int pixblk = blockIdx.x;
    int b = pixblk >> 6;
    int hwb = (pixblk & 63) * 64;
    int p4 = tid & 15, ocg = tid >> 4;
    int p = p4 * 4, oc0 = ocg * 16;
    float acc[16][4];
    #pragma unroll
    for (int i = 0; i < 16; ++i)
        #pragma unroll
        for (int j = 0; j < 4; ++j) acc[i][j] = 0.f;
    const float* op_ = outb + (size_t)b * HID * HW + hwb;
    for (int k0 = 0; k0 < HID; k0 += 32) {
        __syncthreads();
        #pragma unroll
        for (int q = 0; q < 32; ++q) {          // W: 32x256 (transposed layout)
            int idx = tid + q * 256;
            int oc = idx & 255, kk = idx >> 8;
            wl[kk][oc] = woutt[(size_t)(k0 + kk) * CC + oc];
        }
        #pragma unroll
        for (int q = 0; q < 8; ++q) {           // out tile: 32x64
            int idx = tid + q * 256;
            int kk = idx >> 6, pp = idx & 63;
            ol[kk][pp] = op_[(size_t)(k0 + kk) * HW + pp];
        }
        __syncthreads();
        #pragma unroll 4
        for (int kk = 0; kk < 32; ++kk) {
            float4 o4 = *(const float4*)&ol[kk][p];
            float ov[4] = {o4.x, o4.y, o4.z, o4.w};
            #pragma unroll
            for (int i4 = 0; i4 < 4; ++i4) {
                float4 w4 = *(const float4*)&wl[kk][oc0 + i4 * 4];
                float wv[4] = {w4.x, w4.y, w4.z, w4.w};
                #pragma unroll
                for (int ii = 0; ii < 4; ++ii)
                    #pragma unroll
                    for (int j = 0; j < 4; ++j) acc[i4 * 4 + ii][j] += wv[ii] * ov[j];
            }
        }
    }
    float part[4] = {0.f, 0.f, 0.f, 0.f};
    #pragma unroll
    for (int i = 0; i < 16; ++i) {
        float bo = bout[oc0 + i];
        #pragma unroll
        for (int j = 0; j < 4; ++j) { acc[i][j] += bo; part[j] += acc[i][j] * acc[i][j]; }
    }
    #pragma unroll
    for (int j = 0; j < 4; ++j) red[ocg][p + j] = part[j];
    __syncthreads();
    if (tid < 64) {
        float s = 0.f;
        #pragma unroll
        for (int g = 0; g < 16; ++g) s += red[g][tid];
        invs[tid] = 1.0f / fmaxf(sqrtf(s), 1e-12f);
    }
    __syncthreads();
    #pragma unroll
    for (int i = 0; i < 16; ++i) {
        float gs = g2[oc0 + i] * 16.0f;
        float* yp = y + ((size_t)b * CC + oc0 + i) * HW + hwb + p;
        *(float4*)yp = make_float4(acc[i][0] * invs[p + 0] * gs, acc[i][1] * invs[p + 1] * gs,
                                   acc[i][2] * invs[p + 2] * gs, acc[i][3] * invs[p + 3] * gs);
    }
}

extern "C" void kernel_launch(void* const* d_in, const int* in_sizes, int n_in,
                              void* d_out, int out_size, void* d_ws, size_t ws_size,
                              hipStream_t stream) {
    const float* x     = (const float*)d_in[0];
    const float* g1    = (const float*)d_in[1];
    const float* memkv = (const float*)d_in[2];
    const float* wqkv  = (const float*)d_in[3];
    const float* wout  = (const float*)d_in[4];
    const float* bout  = (const float*)d_in[5];
    const float* g2    = (const float*)d_in[6];
    float* y = (float*)d_out;

    float* ws    = (float*)d_ws;
    float* wq2t  = ws;                    // 256*384   =    98304
    float* woutt = wq2t + 98304;          // 128*256   =    32768
    float* rn    = woutt + 32768;         // 131072
    float* kmaxb = rn + 131072;           // 4096
    float* rsumb = kmaxb + 4096;          // 4096
    float* ctxp  = rsumb + 4096;          // 2*131072  =   262144
    float* qkv   = ctxp + 262144;         // 32*384*4096 = 50331648
    float* outb  = qkv + 50331648;        // 32*128*4096 = 16777216
    // total 67,641,344 floats = 270.6 MB of d_ws

    k_prep <<<dim3(256),      dim3(256), 0, stream>>>(wqkv, g1, wout, wq2t, woutt);
    k_rnorm<<<dim3(512),      dim3(256), 0, stream>>>(x, rn);
    k_qkv  <<<dim3(2048, 3),  dim3(256), 0, stream>>>(x, wq2t, rn, qkv);
    k_ksoft<<<dim3(1024),     dim3(256), 0, stream>>>(qkv, memkv, kmaxb, rsumb);
    k_ctx  <<<dim3(256),      dim3(256), 0, stream>>>(qkv, memkv, kmaxb, rsumb, ctxp);
    k_attn <<<dim3(2048),     dim3(256), 0, stream>>>(qkv, ctxp, outb);
    k_final<<<dim3(2048),     dim3(256), 0, stream>>>(outb, woutt, bout, g2, y);
}

// Round 2
// 437.349 us; speedup vs baseline: 1.9471x; 1.9471x over previous
//
#include <hip/hip_runtime.h>
#include <math.h>

#define CC   256
#define HW   4096
#define OC3  384
#define HID  128
#define DH   32
#define NM   4
#define SCALE 0.17677669529663688f  // 32^-0.5

typedef __bf16 bf16x8 __attribute__((ext_vector_type(8)));
typedef float  f32x4  __attribute__((ext_vector_type(4)));

__device__ __forceinline__ ushort f2bf(float x) {
    union { float f; unsigned u; } v; v.f = x;
    unsigned r = v.u + 0x7fffu + ((v.u >> 16) & 1u);   // RNE
    return (ushort)(r >> 16);
}
__device__ __forceinline__ float bf2f(ushort b) {
    union { unsigned u; float f; } v; v.u = ((unsigned)b) << 16; return v.f;
}
__device__ __forceinline__ void g2l16(const void* g, void* l) {
    __builtin_amdgcn_global_load_lds(
        (const __attribute__((address_space(1))) void*)g,
        (__attribute__((address_space(3))) void*)l, 16, 0, 0);
}

// ---------------- prep: wq2t[o][c] = wqkv[o][c]*g1[c]*16 (bf16); woutt = bf16(wout)
__global__ void k_prep(const float* __restrict__ wqkv, const float* __restrict__ g1,
                       const float* __restrict__ wout,
                       ushort* __restrict__ wq2t, ushort* __restrict__ woutt) {
    int o = blockIdx.x, t = threadIdx.x;
    wq2t[(size_t)o * CC + t] = f2bf(wqkv[(size_t)o * CC + t] * g1[t] * 16.0f);
    if (o < CC && t < HID) woutt[(size_t)o * HID + t] = f2bf(wout[(size_t)o * HID + t]);
}

// ---------------- fused rms-norm + transpose + bf16: xnT[b][pix][c] = x*rn
__global__ __launch_bounds__(256) void k_xn(const float* __restrict__ x,
                                            ushort* __restrict__ xnT) {
    __shared__ float xt[256 * 33];
    __shared__ float ps[8 * 33];
    __shared__ float invn[32];
    int tid = threadIdx.x;
    int pix0 = blockIdx.x * 32;
    int b = pix0 >> 12, hw0 = pix0 & 4095;
    int p = tid & 31, cg = tid >> 5;
    const float* xb = x + (size_t)b * CC * HW + hw0;
    #pragma unroll 4
    for (int step = 0; step < 32; ++step) {
        int c = step * 8 + cg;
        xt[c * 33 + p] = xb[(size_t)c * HW + p];
    }
    __syncthreads();
    float s = 0.f;
    #pragma unroll 8
    for (int i = 0; i < 32; ++i) { float v = xt[(cg * 32 + i) * 33 + p]; s += v * v; }
    ps[cg * 33 + p] = s;
    __syncthreads();
    if (tid < 32) {
        float t = 0.f;
        #pragma unroll
        for (int g = 0; g < 8; ++g) t += ps[g * 33 + tid];
        invn[tid] = 1.0f / fmaxf(sqrtf(t), 1e-12f);
    }
    __syncthreads();
    float inv = invn[p];
    ushort* dst = xnT + ((size_t)(pix0 + p)) * CC + cg * 32;
    #pragma unroll
    for (int q = 0; q < 4; ++q) {
        uint4 pk; ushort* o8 = (ushort*)&pk;
        #pragma unroll
        for (int i = 0; i < 8; ++i) o8[i] = f2bf(xt[(cg * 32 + q * 8 + i) * 33 + p] * inv);
        *(uint4*)&dst[q * 8] = pk;
    }
}

// ---------------- qkv MFMA GEMM: 128oc x 128pix tiles, BK=32, bf16 out
__global__ __launch_bounds__(256) void k_qkv(const ushort* __restrict__ wq2t,
        const ushort* __restrict__ xnT, ushort* __restrict__ qkv) {
    __shared__ ushort As[128 * 32];
    __shared__ ushort Bs[128 * 32];
    int tid = threadIdx.x;
    int m0 = blockIdx.x * 128;
    int p0 = blockIdx.y * 128;
    int b  = blockIdx.z;
    int lane = tid & 63, wid = tid >> 6;
    int l15 = tid & 15, quad = (tid >> 4) & 3;
    int wm = wid >> 1, wn = wid & 1;
    int rsub = lane >> 2, csub = (lane & 3) * 8;
    const ushort* Ab = wq2t + (size_t)m0 * CC;
    const ushort* Bb = xnT + ((size_t)(b * HW + p0)) * CC;
    f32x4 acc[4][4];
    #pragma unroll
    for (int i = 0; i < 4; ++i)
        #pragma unroll
        for (int j = 0; j < 4; ++j) acc[i][j] = (f32x4){0.f, 0.f, 0.f, 0.f};
    for (int k0 = 0; k0 < CC; k0 += 32) {
        __syncthreads();
        #pragma unroll
        for (int q = 0; q < 2; ++q) {
            int rw = wid * 32 + q * 16;
            g2l16(Ab + (size_t)(rw + rsub) * CC + k0 + csub, &As[rw * 32]);
            g2l16(Bb + (size_t)(rw + rsub) * CC + k0 + csub, &Bs[rw * 32]);
        }
        __syncthreads();
        bf16x8 af[4], bfr[4];
        #pragma unroll
        for (int mt = 0; mt < 4; ++mt)
            af[mt] = *(const bf16x8*)&As[(wm * 64 + mt * 16 + l15) * 32 + quad * 8];
        #pragma unroll
        for (int nt = 0; nt < 4; ++nt)
            bfr[nt] = *(const bf16x8*)&Bs[(wn * 64 + nt * 16 + l15) * 32 + quad * 8];
        #pragma unroll
        for (int mt = 0; mt < 4; ++mt)
            #pragma unroll
            for (int nt = 0; nt < 4; ++nt)
                acc[mt][nt] = __builtin_amdgcn_mfma_f32_16x16x32_bf16(
                                  af[mt], bfr[nt], acc[mt][nt], 0, 0, 0);
    }
    #pragma unroll
    for (int mt = 0; mt < 4; ++mt) {
        int o = m0 + wm * 64 + mt * 16 + quad * 4;
        #pragma unroll
        for (int nt = 0; nt < 4; ++nt) {
            int pix = p0 + wn * 64 + nt * 16 + l15;
            ushort* dst = qkv + ((size_t)(b * OC3 + o)) * HW + pix;
            #pragma unroll
            for (int r = 0; r < 4; ++r) dst[(size_t)r * HW] = f2bf(acc[mt][nt][r]);
        }
    }
}

// ---------------- k-softmax stats over bf16 k rows
__global__ void k_ksoft(const ushort* __restrict__ qkv, const float* __restrict__ memkv,
                        float* __restrict__ kmaxb, float* __restrict__ rsumb) {
    int row = blockIdx.x * 4 + (threadIdx.x >> 6);
    int lane = threadIdx.x & 63;
    int b = row >> 7, hd = row & 127;
    const ushort* kp = qkv + ((size_t)(b * OC3 + HID + hd)) * HW;
    float m = -1e30f;
    for (int i = lane; i < HW; i += 64) m = fmaxf(m, bf2f(kp[i]));
    #pragma unroll
    for (int s = 1; s < 64; s <<= 1) m = fmaxf(m, __shfl_xor(m, s));
    const float* mk = memkv + hd * NM;
    #pragma unroll
    for (int j = 0; j < NM; ++j) m = fmaxf(m, mk[j]);
    float s = 0.f;
    for (int i = lane; i < HW; i += 64) s += __expf(bf2f(kp[i]) - m);
    #pragma unroll
    for (int t = 1; t < 64; t <<= 1) s += __shfl_xor(s, t);
    #pragma unroll
    for (int j = 0; j < NM; ++j) s += __expf(mk[j] - m);
    if (lane == 0) { kmaxb[row] = m; rsumb[row] = 1.0f / s; }
}

// ---------------- context: ctx[b,h,d,e] = sum_n softk[d,n]*v[e,n]
__global__ __launch_bounds__(256) void k_ctx(const ushort* __restrict__ qkv,
        const float* __restrict__ memkv, const float* __restrict__ kmaxb,
        const float* __restrict__ rsumb, float* __restrict__ ctxp) {
    __shared__ float kl[DH][65];
    __shared__ float vl[DH][65];
    __shared__ float red[256 * 33];
    int tid = threadIdx.x;
    int bh = blockIdx.x >> 1;
    int half = blockIdx.x & 1;
    int b = bh >> 2, h = bh & 3;
    const ushort* kp = qkv + ((size_t)(b * OC3 + HID + h * DH)) * HW + half * 2048;
    const ushort* vp = qkv + ((size_t)(b * OC3 + 2 * HID + h * DH)) * HW + half * 2048;
    int slot = tid & 31, nng = tid >> 5;
    int d0 = (slot >> 2) * 4, e0 = (slot & 3) * 8;
    int rowbase = bh * DH;
    float acc[4][8];
    #pragma unroll
    for (int i = 0; i < 4; ++i)
        #pragma unroll
        for (int j = 0; j < 8; ++j) acc[i][j] = 0.f;
    for (int n0 = 0; n0 < 2048; n0 += 64) {
        __syncthreads();
        #pragma unroll
        for (int q = 0; q < 8; ++q) {
            int idx = tid + q * 256;
            int r = idx >> 6, nn = idx & 63;
            float kraw = bf2f(kp[(size_t)r * HW + n0 + nn]);
            kl[r][nn] = __expf(kraw - kmaxb[rowbase + r]) * rsumb[rowbase + r];
            vl[r][nn] = bf2f(vp[(size_t)r * HW + n0 + nn]);
        }
        __syncthreads();
        #pragma unroll 2
        for (int t = 0; t < 8; ++t) {
            int nn = nng * 8 + t;
            float kv[4], vv[8];
            #pragma unroll
            for (int i = 0; i < 4; ++i) kv[i] = kl[d0 + i][nn];
            #pragma unroll
            for (int j = 0; j < 8; ++j) vv[j] = vl[e0 + j][nn];
            #pragma unroll
            for (int i = 0; i < 4; ++i)
                #pragma unroll
                for (int j = 0; j < 8; ++j) acc[i][j] += kv[i] * vv[j];
        }
    }
    __syncthreads();
    #pragma unroll
    for (int i = 0; i < 4; ++i)
        #pragma unroll
        for (int j = 0; j < 8; ++j) red[tid * 33 + i * 8 + j] = acc[i][j];
    __syncthreads();
    #pragma unroll
    for (int q = 0; q < 4; ++q) {
        int o = tid * 4 + q;
        int d = o >> 5, e = o & 31;
        int sl = (d >> 2) * 4 + (e >> 3);
        int k = (d & 3) * 8 + (e & 7);
        float s = 0.f;
        #pragma unroll
        for (int g = 0; g < 8; ++g) s += red[(g * 32 + sl) * 33 + k];
        if (half == 0) {
            float km = kmaxb[rowbase + d], rsm = rsumb[rowbase + d];
            #pragma unroll
            for (int m = 0; m < NM; ++m) {
                float kw = __expf(memkv[(h * DH + d) * NM + m] - km) * rsm;
                s += kw * memkv[512 + (h * DH + e) * NM + m];
            }
        }
        ctxp[(size_t)half * 131072 + (size_t)bh * 1024 + o] = s;
    }
}

// ---------------- q softmax + apply context -> outbT[b][pix][hid] bf16
__global__ __launch_bounds__(256) void k_attn(const ushort* __restrict__ qkv,
        const float* __restrict__ ctxp, ushort* __restrict__ outbT) {
    __shared__ float qs[128][68];
    __shared__ float cs[4096];
    int tid = threadIdx.x;
    int pixblk = blockIdx.x;
    int b = pixblk >> 6;
    int hwb = (pixblk & 63) * 64;
    const ushort* qp = qkv + (size_t)b * OC3 * HW + hwb;
    #pragma unroll
    for (int q = 0; q < 32; ++q) {
        int idx = tid + q * 256;
        int r = idx >> 6, p = idx & 63;
        qs[r][p] = bf2f(qp[(size_t)r * HW + p]);
    }
    #pragma unroll
    for (int q = 0; q < 16; ++q) {
        int i = tid + q * 256;
        cs[i] = ctxp[(size_t)b * 4096 + i] + ctxp[131072 + (size_t)b * 4096 + i];
    }
    __syncthreads();
    {
        int h = tid >> 6, p = tid & 63;
        float m = -1e30f;
        #pragma unroll
        for (int d = 0; d < DH; ++d) m = fmaxf(m, qs[h * DH + d][p]);
        float s = 0.f;
        #pragma unroll
        for (int d = 0; d < DH; ++d) s += __expf(qs[h * DH + d][p] - m);
        float r_ = SCALE / s;
        #pragma unroll
        for (int d = 0; d < DH; ++d) qs[h * DH + d][p] = __expf(qs[h * DH + d][p] - m) * r_;
    }
    __syncthreads();
    int p4 = tid & 15, eg = tid >> 4;
    int p = p4 * 4, r0 = eg * 8;
    int h = r0 >> 5, el = r0 & 31;
    float acc[8][4];
    #pragma unroll
    for (int i = 0; i < 8; ++i)
        #pragma unroll
        for (int j = 0; j < 4; ++j) acc[i][j] = 0.f;
    #pragma unroll 4
    for (int d = 0; d < DH; ++d) {
        float4 q4 = *(const float4*)&qs[h * DH + d][p];
        float qv[4] = {q4.x, q4.y, q4.z, q4.w};
        #pragma unroll
        for (int i = 0; i < 8; ++i) {
            float cv = cs[(h * DH + d) * DH + el + i];
            #pragma unroll
            for (int j = 0; j < 4; ++j) acc[i][j] += cv * qv[j];
        }
    }
    #pragma unroll
    for (int j = 0; j < 4; ++j) {
        uint4 pk; ushort* o8 = (ushort*)&pk;
        #pragma unroll
        for (int i = 0; i < 8; ++i) o8[i] = f2bf(acc[i][j]);
        *(uint4*)&outbT[((size_t)(b * HW + hwb + p + j)) * HID + r0] = pk;
    }
}

// ---------------- final MFMA GEMM 256oc x 64pix + fused bias + rms-norm*g2*16
__global__ __launch_bounds__(256) void k_final(const ushort* __restrict__ outbT,
        const ushort* __restrict__ woutt, const float* __restrict__ bout,
        const float* __restrict__ g2, float* __restrict__ y) {
    __shared__ ushort As[256 * 32];
    __shared__ ushort Bs[64 * 32];
    __shared__ float red[64 * 17];
    __shared__ float invs[64];
    __shared__ float bl[256];
    __shared__ float gl[256];
    int tid = threadIdx.x;
    int p0 = blockIdx.x * 64;
    int b  = blockIdx.y;
    int lane = tid & 63, wid = tid >> 6;
    int l15 = tid & 15, quad = (tid >> 4) & 3;
    int rsub = lane >> 2, csub = (lane & 3) * 8;
    bl[tid] = bout[tid];
    gl[tid] = g2[tid];
    const ushort* Bb = outbT + ((size_t)(b * HW + p0)) * HID;
    f32x4 acc[4][4];
    #pragma unroll
    for (int i = 0; i < 4; ++i)
        #pragma unroll
        for (int j = 0; j < 4; ++j) acc[i][j] = (f32x4){0.f, 0.f, 0.f, 0.f};
    for (int k0 = 0; k0 < HID; k0 += 32) {
        __syncthreads();
        #pragma unroll
        for (int q = 0; q < 4; ++q) {
            int rw = wid * 64 + q * 16;
            g2l16(woutt + (size_t)(rw + rsub) * HID + k0 + csub, &As[rw * 32]);
        }
        {
            int rw = wid * 16;
            g2l16(Bb + (size_t)(rw + rsub) * HID + k0 + csub, &Bs[rw * 32]);
        }
        __syncthreads();
        bf16x8 af[4], bfr[4];
        #pragma unroll
        for (int mt = 0; mt < 4; ++mt)
            af[mt] = *(const bf16x8*)&As[(wid * 64 + mt * 16 + l15) * 32 + quad * 8];
        #pragma unroll
        for (int nt = 0; nt < 4; ++nt)
            bfr[nt] = *(const bf16x8*)&Bs[(nt * 16 + l15) * 32 + quad * 8];
        #pragma unroll
        for (int mt = 0; mt < 4; ++mt)
            #pragma unroll
            for (int nt = 0; nt < 4; ++nt)
                acc[mt][nt] = __builtin_amdgcn_mfma_f32_16x16x32_bf16(
                                  af[mt], bfr[nt], acc[mt][nt], 0, 0, 0);
    }
    float part[4] = {0.f, 0.f, 0.f, 0.f};
    #pragma unroll
    for (int mt = 0; mt < 4; ++mt)
        #pragma unroll
        for (int r = 0; r < 4; ++r) {
            int oc = wid * 64 + mt * 16 + quad * 4 + r;
            float bo = bl[oc];
            #pragma unroll
            for (int nt = 0; nt < 4; ++nt) {
                float v = acc[mt][nt][r] + bo;
                acc[mt][nt][r] = v;
                part[nt] += v * v;
            }
        }
    #pragma unroll
    for (int nt = 0; nt < 4; ++nt)
        red[(nt * 16 + l15) * 17 + wid * 4 + quad] = part[nt];
    __syncthreads();
    if (tid < 64) {
        float s = 0.f;
        #pragma unroll
        for (int g = 0; g < 16; ++g) s += red[tid * 17 + g];
        invs[tid] = 1.0f / fmaxf(sqrtf(s), 1e-12f);
    }
    __syncthreads();
    #pragma unroll
    for (int mt = 0; mt < 4; ++mt)
        #pragma unroll
        for (int nt = 0; nt < 4; ++nt) {
            int pix = nt * 16 + l15;
            float iv = invs[pix];
            #pragma unroll
            for (int r = 0; r < 4; ++r) {
                int oc = wid * 64 + mt * 16 + quad * 4 + r;
                y[((size_t)(b * CC + oc)) * HW + p0 + pix] = acc[mt][nt][r] * iv * gl[oc] * 16.0f;
            }
        }
}

extern "C" void kernel_launch(void* const* d_in, const int* in_sizes, int n_in,
                              void* d_out, int out_size, void* d_ws, size_t ws_size,
                              hipStream_t stream) {
    const float* x     = (const float*)d_in[0];
    const float* g1    = (const float*)d_in[1];
    const float* memkv = (const float*)d_in[2];
    const float* wqkv  = (const float*)d_in[3];
    const float* wout  = (const float*)d_in[4];
    const float* bout  = (const float*)d_in[5];
    const float* g2    = (const float*)d_in[6];
    float* y = (float*)d_out;

    char* w = (char*)d_ws;
    ushort* wq2t  = (ushort*)w;  w += (size_t)OC3 * CC * 2;        //   196,608 B
    ushort* woutt = (ushort*)w;  w += (size_t)CC * HID * 2;        //    65,536 B
    float*  kmaxb = (float*)w;   w += 4096 * 4;
    float*  rsumb = (float*)w;   w += 4096 * 4;
    float*  ctxp  = (float*)w;   w += 262144 * 4;                  // 1,048,576 B
    ushort* xnT   = (ushort*)w;  w += (size_t)32 * HW * CC * 2;    //  67,108,864 B
    ushort* qkv   = (ushort*)w;  w += (size_t)32 * OC3 * HW * 2;   // 100,663,296 B
    ushort* outbT = (ushort*)w;  w += (size_t)32 * HW * HID * 2;   //  33,554,432 B
    // total ~202.7 MB of d_ws

    k_prep <<<dim3(384),        dim3(256), 0, stream>>>(wqkv, g1, wout, wq2t, woutt);
    k_xn   <<<dim3(4096),       dim3(256), 0, stream>>>(x, xnT);
    k_qkv  <<<dim3(3, 32, 32),  dim3(256), 0, stream>>>(wq2t, xnT, qkv);
    k_ksoft<<<dim3(1024),       dim3(256), 0, stream>>>(qkv, memkv, kmaxb, rsumb);
    k_ctx  <<<dim3(256),        dim3(256), 0, stream>>>(qkv, memkv, kmaxb, rsumb, ctxp);
    k_attn <<<dim3(2048),       dim3(256), 0, stream>>>(qkv, ctxp, outbT);
    k_final<<<dim3(64, 32),     dim3(256), 0, stream>>>(outbT, woutt, bout, g2, y);
}

// Round 3
// 420.051 us; speedup vs baseline: 2.0273x; 1.0412x over previous
//
#include <hip/hip_runtime.h>
#include <math.h>

#define CC   256
#define HW   4096
#define OC3  384
#define HID  128
#define DH   32
#define NM   4
#define NPART 8
#define SCALE 0.17677669529663688f  // 32^-0.5

typedef __bf16 bf16x8 __attribute__((ext_vector_type(8)));
typedef float  f32x4  __attribute__((ext_vector_type(4)));

__device__ __forceinline__ ushort f2bf(float x) {
    union { float f; unsigned u; } v; v.f = x;
    unsigned r = v.u + 0x7fffu + ((v.u >> 16) & 1u);   // RNE
    return (ushort)(r >> 16);
}
__device__ __forceinline__ float bf2f(ushort b) {
    union { unsigned u; float f; } v; v.u = ((unsigned)b) << 16; return v.f;
}
__device__ __forceinline__ void g2l16(const void* g, void* l) {
    __builtin_amdgcn_global_load_lds(
        (const __attribute__((address_space(1))) void*)g,
        (__attribute__((address_space(3))) void*)l, 16, 0, 0);
}

// ---------------- prep: wq2t[o][c] = wqkv[o][c]*g1[c]*16 (bf16); woutt = bf16(wout)
__global__ void k_prep(const float* __restrict__ wqkv, const float* __restrict__ g1,
                       const float* __restrict__ wout,
                       ushort* __restrict__ wq2t, ushort* __restrict__ woutt) {
    int o = blockIdx.x, t = threadIdx.x;
    wq2t[(size_t)o * CC + t] = f2bf(wqkv[(size_t)o * CC + t] * g1[t] * 16.0f);
    if (o < CC && t < HID) woutt[(size_t)o * HID + t] = f2bf(wout[(size_t)o * HID + t]);
}

// ---------------- fused rms-norm + transpose + bf16: xnT[b][pix][c]
__global__ __launch_bounds__(256) void k_xn(const float* __restrict__ x,
                                            ushort* __restrict__ xnT) {
    __shared__ float xt[256 * 33];
    __shared__ float ps[8 * 33];
    __shared__ float invn[32];
    int tid = threadIdx.x;
    int pix0 = blockIdx.x * 32;
    int b = pix0 >> 12, hw0 = pix0 & 4095;
    int p = tid & 31, cg = tid >> 5;
    const float* xb = x + (size_t)b * CC * HW + hw0;
    #pragma unroll 4
    for (int step = 0; step < 32; ++step) {
        int c = step * 8 + cg;
        xt[c * 33 + p] = xb[(size_t)c * HW + p];
    }
    __syncthreads();
    float s = 0.f;
    #pragma unroll 8
    for (int i = 0; i < 32; ++i) { float v = xt[(cg * 32 + i) * 33 + p]; s += v * v; }
    ps[cg * 33 + p] = s;
    __syncthreads();
    if (tid < 32) {
        float t = 0.f;
        #pragma unroll
        for (int g = 0; g < 8; ++g) t += ps[g * 33 + tid];
        invn[tid] = 1.0f / fmaxf(sqrtf(t), 1e-12f);
    }
    __syncthreads();
    float inv = invn[p];
    ushort* dst = xnT + ((size_t)(pix0 + p)) * CC + cg * 32;
    #pragma unroll
    for (int q = 0; q < 4; ++q) {
        uint4 pk; ushort* o8 = (ushort*)&pk;
        #pragma unroll
        for (int i = 0; i < 8; ++i) o8[i] = f2bf(xt[(cg * 32 + q * 8 + i) * 33 + p] * inv);
        *(uint4*)&dst[q * 8] = pk;
    }
}

// ---------------- qkv MFMA GEMM: 128oc x 128pix tiles, BK=32, bf16 out
__global__ __launch_bounds__(256) void k_qkv(const ushort* __restrict__ wq2t,
        const ushort* __restrict__ xnT, ushort* __restrict__ qkv) {
    __shared__ ushort As[128 * 32];
    __shared__ ushort Bs[128 * 32];
    int tid = threadIdx.x;
    int m0 = blockIdx.x * 128;
    int p0 = blockIdx.y * 128;
    int b  = blockIdx.z;
    int lane = tid & 63, wid = tid >> 6;
    int l15 = tid & 15, quad = (tid >> 4) & 3;
    int wm = wid >> 1, wn = wid & 1;
    int rsub = lane >> 2, csub = (lane & 3) * 8;
    const ushort* Ab = wq2t + (size_t)m0 * CC;
    const ushort* Bb = xnT + ((size_t)(b * HW + p0)) * CC;
    f32x4 acc[4][4];
    #pragma unroll
    for (int i = 0; i < 4; ++i)
        #pragma unroll
        for (int j = 0; j < 4; ++j) acc[i][j] = (f32x4){0.f, 0.f, 0.f, 0.f};
    for (int k0 = 0; k0 < CC; k0 += 32) {
        __syncthreads();
        #pragma unroll
        for (int q = 0; q < 2; ++q) {
            int rw = wid * 32 + q * 16;
            g2l16(Ab + (size_t)(rw + rsub) * CC + k0 + csub, &As[rw * 32]);
            g2l16(Bb + (size_t)(rw + rsub) * CC + k0 + csub, &Bs[rw * 32]);
        }
        __syncthreads();
        bf16x8 af[4], bfr[4];
        #pragma unroll
        for (int mt = 0; mt < 4; ++mt)
            af[mt] = *(const bf16x8*)&As[(wm * 64 + mt * 16 + l15) * 32 + quad * 8];
        #pragma unroll
        for (int nt = 0; nt < 4; ++nt)
            bfr[nt] = *(const bf16x8*)&Bs[(wn * 64 + nt * 16 + l15) * 32 + quad * 8];
        #pragma unroll
        for (int mt = 0; mt < 4; ++mt)
            #pragma unroll
            for (int nt = 0; nt < 4; ++nt)
                acc[mt][nt] = __builtin_amdgcn_mfma_f32_16x16x32_bf16(
                                  af[mt], bfr[nt], acc[mt][nt], 0, 0, 0);
    }
    #pragma unroll
    for (int mt = 0; mt < 4; ++mt) {
        int o = m0 + wm * 64 + mt * 16 + quad * 4;
        #pragma unroll
        for (int nt = 0; nt < 4; ++nt) {
            int pix = p0 + wn * 64 + nt * 16 + l15;
            ushort* dst = qkv + ((size_t)(b * OC3 + o)) * HW + pix;
            #pragma unroll
            for (int r = 0; r < 4; ++r) dst[(size_t)r * HW] = f2bf(acc[mt][nt][r]);
        }
    }
}

// ---------------- k-softmax stats over bf16 k rows
__global__ void k_ksoft(const ushort* __restrict__ qkv, const float* __restrict__ memkv,
                        float* __restrict__ kmaxb, float* __restrict__ rsumb) {
    int row = blockIdx.x * 4 + (threadIdx.x >> 6);
    int lane = threadIdx.x & 63;
    int b = row >> 7, hd = row & 127;
    const ushort* kp = qkv + ((size_t)(b * OC3 + HID + hd)) * HW;
    float m = -1e30f;
    for (int i = lane; i < HW; i += 64) m = fmaxf(m, bf2f(kp[i]));
    #pragma unroll
    for (int s = 1; s < 64; s <<= 1) m = fmaxf(m, __shfl_xor(m, s));
    const float* mk = memkv + hd * NM;
    #pragma unroll
    for (int j = 0; j < NM; ++j) m = fmaxf(m, mk[j]);
    float s = 0.f;
    for (int i = lane; i < HW; i += 64) s += __expf(bf2f(kp[i]) - m);
    #pragma unroll
    for (int t = 1; t < 64; t <<= 1) s += __shfl_xor(s, t);
    #pragma unroll
    for (int j = 0; j < NM; ++j) s += __expf(mk[j] - m);
    if (lane == 0) { kmaxb[row] = m; rsumb[row] = 1.0f / s; }
}

// ---------------- context partials: ctxp[part][bh][d*32+e], n split 8 ways
__global__ __launch_bounds__(256) void k_ctx(const ushort* __restrict__ qkv,
        const float* __restrict__ memkv, const float* __restrict__ kmaxb,
        const float* __restrict__ rsumb, float* __restrict__ ctxp) {
    __shared__ float kl[DH][65];
    __shared__ float vl[DH][65];
    __shared__ float red[256 * 33];
    int tid = threadIdx.x;
    int bh = blockIdx.x;            // 0..127
    int part = blockIdx.y;          // 0..7
    int b = bh >> 2, h = bh & 3;
    const ushort* kp = qkv + ((size_t)(b * OC3 + HID + h * DH)) * HW + part * 512;
    const ushort* vp = qkv + ((size_t)(b * OC3 + 2 * HID + h * DH)) * HW + part * 512;
    int slot = tid & 31, nng = tid >> 5;
    int d0 = (slot >> 2) * 4, e0 = (slot & 3) * 8;
    int rowbase = bh * DH;
    float acc[4][8];
    #pragma unroll
    for (int i = 0; i < 4; ++i)
        #pragma unroll
        for (int j = 0; j < 8; ++j) acc[i][j] = 0.f;
    for (int n0 = 0; n0 < 512; n0 += 64) {
        __syncthreads();
        #pragma unroll
        for (int q = 0; q < 8; ++q) {
            int idx = tid + q * 256;
            int r = idx >> 6, nn = idx & 63;
            float kraw = bf2f(kp[(size_t)r * HW + n0 + nn]);
            kl[r][nn] = __expf(kraw - kmaxb[rowbase + r]) * rsumb[rowbase + r];
            vl[r][nn] = bf2f(vp[(size_t)r * HW + n0 + nn]);
        }
        __syncthreads();
        #pragma unroll 2
        for (int t = 0; t < 8; ++t) {
            int nn = nng * 8 + t;
            float kv[4], vv[8];
            #pragma unroll
            for (int i = 0; i < 4; ++i) kv[i] = kl[d0 + i][nn];
            #pragma unroll
            for (int j = 0; j < 8; ++j) vv[j] = vl[e0 + j][nn];
            #pragma unroll
            for (int i = 0; i < 4; ++i)
                #pragma unroll
                for (int j = 0; j < 8; ++j) acc[i][j] += kv[i] * vv[j];
        }
    }
    __syncthreads();
    #pragma unroll
    for (int i = 0; i < 4; ++i)
        #pragma unroll
        for (int j = 0; j < 8; ++j) red[tid * 33 + i * 8 + j] = acc[i][j];
    __syncthreads();
    #pragma unroll
    for (int q = 0; q < 4; ++q) {
        int o = tid * 4 + q;
        int d = o >> 5, e = o & 31;
        int sl = (d >> 2) * 4 + (e >> 3);
        int k = (d & 3) * 8 + (e & 7);
        float s = 0.f;
        #pragma unroll
        for (int g = 0; g < 8; ++g) s += red[(g * 32 + sl) * 33 + k];
        if (part == 0) {   // memory-kv contribution added once
            float km = kmaxb[rowbase + d], rsm = rsumb[rowbase + d];
            #pragma unroll
            for (int m = 0; m < NM; ++m) {
                float kw = __expf(memkv[(h * DH + d) * NM + m] - km) * rsm;
                s += kw * memkv[512 + (h * DH + e) * NM + m];
            }
        }
        ctxp[(size_t)part * 131072 + (size_t)bh * 1024 + o] = s;
    }
}

// ---------------- fused: q-softmax + ctx apply (MFMA) + out-proj (MFMA)
//                  + bias + rms-norm*g2, one block per (b, 64-pixel tile)
__global__ __launch_bounds__(256) void k_attn_final(const ushort* __restrict__ qkv,
        const float* __restrict__ ctxp, const ushort* __restrict__ woutt,
        const float* __restrict__ bout, const float* __restrict__ g2,
        float* __restrict__ y) {
    __shared__ __align__(16) char smem[51712];
    ushort* qs   = (ushort*)smem;              // [128][68]  q tile (row-major, pix fast)
    ushort* outT = (ushort*)smem;              // [64][136]  aliases qs (dead after softmax)
    ushort* sq   = (ushort*)(smem + 17408);    // [64][136]  softmaxed q, [pix][hid]
    ushort* Asm  = (ushort*)(smem + 17408);    // [256][32]  aliases sq (dead after stage 3)
    ushort* ctxT = (ushort*)(smem + 34816);    // [128][40]  ctx^T [hid][d]
    float*  red  = (float*)(smem + 45056);     // [64][17]
    float*  invs = (float*)(smem + 49408);     // [64]
    float*  bl   = (float*)(smem + 49664);     // [256]
    float*  gl   = (float*)(smem + 50688);     // [256]
    int tid = threadIdx.x;
    int b = blockIdx.y;
    int hwb = blockIdx.x * 64;
    int lane = tid & 63, wid = tid >> 6;
    int l15 = tid & 15, quad = (tid >> 4) & 3;
    bl[tid] = bout[tid];
    gl[tid] = g2[tid];

    // ---- load q tile: 128 rows x 64 pix
    const ushort* qp = qkv + ((size_t)b * OC3) * HW + hwb;
    #pragma unroll
    for (int i = 0; i < 8; ++i) {
        int flat = i * 1024 + tid * 4;
        int r = flat >> 6, p = flat & 63;
        *(uint2*)&qs[r * 68 + p] = *(const uint2*)&qp[(size_t)r * HW + p];
    }
    // ---- load ctx (sum 8 partials), transpose to [hid][d] bf16
    {
        int rem = tid & 63;
        int d = rem >> 1, e0 = (rem & 1) * 16;
        const float* cb = ctxp + (size_t)b * 4096 + wid * 1024 + d * 32 + e0;
        float cv[16];
        #pragma unroll
        for (int i = 0; i < 16; ++i) cv[i] = 0.f;
        #pragma unroll
        for (int part = 0; part < NPART; ++part)
            #pragma unroll
            for (int i = 0; i < 16; ++i) cv[i] += cb[(size_t)part * 131072 + i];
        #pragma unroll
        for (int i = 0; i < 16; ++i)
            ctxT[(wid * 32 + e0 + i) * 40 + d] = f2bf(cv[i]);
    }
    __syncthreads();

    // ---- softmax over d per (h=wid, p=lane); write sq[pix][hid] bf16
    {
        float vd[32];
        float m = -1e30f;
        #pragma unroll
        for (int dd = 0; dd < 32; ++dd) {
            float v = bf2f(qs[(wid * 32 + dd) * 68 + lane]);
            vd[dd] = v; m = fmaxf(m, v);
        }
        float s = 0.f;
        #pragma unroll
        for (int dd = 0; dd < 32; ++dd) { float e = __expf(vd[dd] - m); vd[dd] = e; s += e; }
        float r_ = SCALE / s;
        #pragma unroll
        for (int qI = 0; qI < 4; ++qI) {
            uint4 pk; ushort* o8 = (ushort*)&pk;
            #pragma unroll
            for (int i = 0; i < 8; ++i) o8[i] = f2bf(vd[qI * 8 + i] * r_);
            *(uint4*)&sq[lane * 136 + wid * 32 + qI * 8] = pk;
        }
    }
    __syncthreads();

    // ---- stage 3 MFMA: out[pix][e] = sum_d softq[pix][d] * ctx[h][d][e], wave=head
    f32x4 acc3[4][2];
    #pragma unroll
    for (int i = 0; i < 4; ++i)
        #pragma unroll
        for (int j = 0; j < 2; ++j) acc3[i][j] = (f32x4){0.f, 0.f, 0.f, 0.f};
    {
        bf16x8 a3[4], b3[2];
        #pragma unroll
        for (int mt = 0; mt < 4; ++mt)
            a3[mt] = *(const bf16x8*)&sq[(mt * 16 + l15) * 136 + wid * 32 + quad * 8];
        #pragma unroll
        for (int nt = 0; nt < 2; ++nt)
            b3[nt] = *(const bf16x8*)&ctxT[(wid * 32 + nt * 16 + l15) * 40 + quad * 8];
        #pragma unroll
        for (int mt = 0; mt < 4; ++mt)
            #pragma unroll
            for (int nt = 0; nt < 2; ++nt)
                acc3[mt][nt] = __builtin_amdgcn_mfma_f32_16x16x32_bf16(
                                   a3[mt], b3[nt], acc3[mt][nt], 0, 0, 0);
    }
    __syncthreads();   // all sq/qs reads done; outT (alias qs) about to be written
    #pragma unroll
    for (int mt = 0; mt < 4; ++mt)
        #pragma unroll
        for (int nt = 0; nt < 2; ++nt)
            #pragma unroll
            for (int r = 0; r < 4; ++r)
                outT[(mt * 16 + quad * 4 + r) * 136 + wid * 32 + nt * 16 + l15] =
                    f2bf(acc3[mt][nt][r]);

    // ---- stage 4 MFMA: y0[oc][pix] = sum_k wout[oc][k] * outT[pix][k]
    f32x4 acc[4][4];
    #pragma unroll
    for (int i = 0; i < 4; ++i)
        #pragma unroll
        for (int j = 0; j < 4; ++j) acc[i][j] = (f32x4){0.f, 0.f, 0.f, 0.f};
    int rsub = lane >> 2, csub = (lane & 3) * 8;
    for (int k0 = 0; k0 < HID; k0 += 32) {
        __syncthreads();    // protects Asm (aliases sq on first iter, reuse after)
        #pragma unroll
        for (int q = 0; q < 4; ++q) {
            int rw = wid * 64 + q * 16;
            g2l16(woutt + (size_t)(rw + rsub) * HID + k0 + csub, &Asm[rw * 32]);
        }
        __syncthreads();
        bf16x8 af[4], bfr[4];
        #pragma unroll
        for (int mt = 0; mt < 4; ++mt)
            af[mt] = *(const bf16x8*)&Asm[(wid * 64 + mt * 16 + l15) * 32 + quad * 8];
        #pragma unroll
        for (int nt = 0; nt < 4; ++nt)
            bfr[nt] = *(const bf16x8*)&outT[(nt * 16 + l15) * 136 + k0 + quad * 8];
        #pragma unroll
        for (int mt = 0; mt < 4; ++mt)
            #pragma unroll
            for (int nt = 0; nt < 4; ++nt)
                acc[mt][nt] = __builtin_amdgcn_mfma_f32_16x16x32_bf16(
                                  af[mt], bfr[nt], acc[mt][nt], 0, 0, 0);
    }

    // ---- epilogue: bias, rms-norm over 256 oc, *g2*16
    float part[4] = {0.f, 0.f, 0.f, 0.f};
    #pragma unroll
    for (int mt = 0; mt < 4; ++mt)
        #pragma unroll
        for (int r = 0; r < 4; ++r) {
            int oc = wid * 64 + mt * 16 + quad * 4 + r;
            float bo = bl[oc];
            #pragma unroll
            for (int nt = 0; nt < 4; ++nt) {
                float v = acc[mt][nt][r] + bo;
                acc[mt][nt][r] = v;
                part[nt] += v * v;
            }
        }
    __syncthreads();
    #pragma unroll
    for (int nt = 0; nt < 4; ++nt)
        red[(nt * 16 + l15) * 17 + wid * 4 + quad] = part[nt];
    __syncthreads();
    if (tid < 64) {
        float s = 0.f;
        #pragma unroll
        for (int g = 0; g < 16; ++g) s += red[tid * 17 + g];
        invs[tid] = 1.0f / fmaxf(sqrtf(s), 1e-12f);
    }
    __syncthreads();
    #pragma unroll
    for (int mt = 0; mt < 4; ++mt)
        #pragma unroll
        for (int nt = 0; nt < 4; ++nt) {
            int pix = nt * 16 + l15;
            float iv = invs[pix];
            #pragma unroll
            for (int r = 0; r < 4; ++r) {
                int oc = wid * 64 + mt * 16 + quad * 4 + r;
                y[((size_t)(b * CC + oc)) * HW + hwb + pix] = acc[mt][nt][r] * iv * gl[oc] * 16.0f;
            }
        }
}

extern "C" void kernel_launch(void* const* d_in, const int* in_sizes, int n_in,
                              void* d_out, int out_size, void* d_ws, size_t ws_size,
                              hipStream_t stream) {
    const float* x     = (const float*)d_in[0];
    const float* g1    = (const float*)d_in[1];
    const float* memkv = (const float*)d_in[2];
    const float* wqkv  = (const float*)d_in[3];
    const float* wout  = (const float*)d_in[4];
    const float* bout  = (const float*)d_in[5];
    const float* g2    = (const float*)d_in[6];
    float* y = (float*)d_out;

    char* w = (char*)d_ws;
    ushort* wq2t  = (ushort*)w;  w += (size_t)OC3 * CC * 2;
    ushort* woutt = (ushort*)w;  w += (size_t)CC * HID * 2;
    float*  kmaxb = (float*)w;   w += 4096 * 4;
    float*  rsumb = (float*)w;   w += 4096 * 4;
    float*  ctxp  = (float*)w;   w += (size_t)NPART * 131072 * 4;  // 4 MB
    ushort* xnT   = (ushort*)w;  w += (size_t)32 * HW * CC * 2;    // 67 MB
    ushort* qkv   = (ushort*)w;  w += (size_t)32 * OC3 * HW * 2;   // 100 MB

    k_prep      <<<dim3(384),       dim3(256), 0, stream>>>(wqkv, g1, wout, wq2t, woutt);
    k_xn        <<<dim3(4096),      dim3(256), 0, stream>>>(x, xnT);
    k_qkv       <<<dim3(3, 32, 32), dim3(256), 0, stream>>>(wq2t, xnT, qkv);
    k_ksoft     <<<dim3(1024),      dim3(256), 0, stream>>>(qkv, memkv, kmaxb, rsumb);
    k_ctx       <<<dim3(128, 8),    dim3(256), 0, stream>>>(qkv, memkv, kmaxb, rsumb, ctxp);
    k_attn_final<<<dim3(64, 32),    dim3(256), 0, stream>>>(qkv, ctxp, woutt, bout, g2, y);
}